// Round 1
// baseline (595.438 us; speedup 1.0000x reference)
//
#include <hip/hip_runtime.h>

#define TT 256
#define BB 2048
#define DIN 128
#define DWROW 132           // D + H
#define INV2PI 0.15915494309189535f
#define LOG2E  1.4426950408889634f

__device__ __forceinline__ float sigm(float x) {
    // 1/(1+e^-x) via native exp2 + rcp
    float e = __builtin_amdgcn_exp2f(-LOG2E * x);
    return __builtin_amdgcn_rcpf(1.0f + e);
}
__device__ __forceinline__ float tanh_f(float x) {
    // 1 - 2/(1+e^{2x})
    float e = __builtin_amdgcn_exp2f((2.0f * LOG2E) * x);
    return 1.0f - 2.0f * __builtin_amdgcn_rcpf(1.0f + e);
}

// Phase 1: Ax[row][g*4+w] = (x[row,:] . W_g[w,:128] + b_g[w] + th_g[w]) * INV2PI
__global__ __launch_bounds__(256) void qlstm_phase1(
    const float* __restrict__ x,
    const float* __restrict__ Wf, const float* __restrict__ bf, const float* __restrict__ thf,
    const float* __restrict__ Wi, const float* __restrict__ bi, const float* __restrict__ thi,
    const float* __restrict__ Wu, const float* __restrict__ bu, const float* __restrict__ thu,
    const float* __restrict__ Wo, const float* __restrict__ bo, const float* __restrict__ tho,
    float* __restrict__ Ax)
{
    const int row = blockIdx.x * 256 + threadIdx.x;   // t*B + b
    const float* Ws[4]  = {Wf, Wi, Wu, Wo};
    const float* bs[4]  = {bf, bi, bu, bo};
    const float* ths[4] = {thf, thi, thu, tho};

    float acc[16];
#pragma unroll
    for (int g = 0; g < 4; ++g)
#pragma unroll
        for (int w = 0; w < 4; ++w)
            acc[g * 4 + w] = bs[g][w] + ths[g][w];

    const float4* xr = (const float4*)(x + (size_t)row * DIN);
#pragma unroll 8
    for (int j4 = 0; j4 < DIN / 4; ++j4) {
        float4 xv = xr[j4];
#pragma unroll
        for (int g = 0; g < 4; ++g) {
#pragma unroll
            for (int w = 0; w < 4; ++w) {
                const float* wr = Ws[g] + w * DWROW + 4 * j4;  // wave-uniform -> s_load
                float a = acc[g * 4 + w];
                a = fmaf(xv.x, wr[0], a);
                a = fmaf(xv.y, wr[1], a);
                a = fmaf(xv.z, wr[2], a);
                a = fmaf(xv.w, wr[3], a);
                acc[g * 4 + w] = a;
            }
        }
    }

    float4* outp = (float4*)(Ax + (size_t)row * 16);
#pragma unroll
    for (int q = 0; q < 4; ++q) {
        float4 v;
        v.x = acc[q * 4 + 0] * INV2PI;
        v.y = acc[q * 4 + 1] * INV2PI;
        v.z = acc[q * 4 + 2] * INV2PI;
        v.w = acc[q * 4 + 3] * INV2PI;
        outp[q] = v;
    }
}

// Phase 2: sequential recurrence, one thread per batch element.
__global__ __launch_bounds__(64) void qlstm_phase2(
    const float* __restrict__ Ax,
    const float* __restrict__ Wf, const float* __restrict__ Wi,
    const float* __restrict__ Wu, const float* __restrict__ Wo,
    float* __restrict__ out)
{
    const int b = blockIdx.x * 64 + threadIdx.x;
    const float* Ws[4] = {Wf, Wi, Wu, Wo};

    // h-part of W, pre-scaled by 1/2pi (wave-uniform loads)
    float Wh[4][4][4];
#pragma unroll
    for (int g = 0; g < 4; ++g)
#pragma unroll
        for (int w = 0; w < 4; ++w)
#pragma unroll
            for (int j = 0; j < 4; ++j)
                Wh[g][w][j] = Ws[g][w * DWROW + DIN + j] * INV2PI;

    float h[4] = {0.f, 0.f, 0.f, 0.f};
    float c[4] = {0.f, 0.f, 0.f, 0.f};

    const float4* ap = (const float4*)(Ax + (size_t)b * 16);
    const size_t astride = (size_t)BB * 4;   // float4 units per timestep

    float4 cur[4], n1[4];
#pragma unroll
    for (int q = 0; q < 4; ++q) cur[q] = ap[q];
#pragma unroll
    for (int q = 0; q < 4; ++q) n1[q] = ap[astride + q];

    float* outh = out + (size_t)b * 4;

    for (int t = 0; t < TT; ++t) {
        // prefetch 2 ahead (clamped)
        int tn = (t + 2 < TT) ? (t + 2) : (TT - 1);
        float4 n2[4];
#pragma unroll
        for (int q = 0; q < 4; ++q) n2[q] = ap[(size_t)tn * astride + q];

        float G[4][4];
#pragma unroll
        for (int g = 0; g < 4; ++g) {
            float aa[4] = {cur[g].x, cur[g].y, cur[g].z, cur[g].w};
            float z[4];
#pragma unroll
            for (int w = 0; w < 4; ++w) {
                float a = aa[w];
                a = fmaf(h[0], Wh[g][w][0], a);
                a = fmaf(h[1], Wh[g][w][1], a);
                a = fmaf(h[2], Wh[g][w][2], a);
                a = fmaf(h[3], Wh[g][w][3], a);
                z[w] = __builtin_amdgcn_cosf(a);   // cos(2*pi*a); inputs pre-scaled
            }
            float z01 = z[0] * z[1];
            float z12 = z[1] * z[2];
            G[g][0] = z12 * z[3];
            G[g][1] = z01;
            G[g][2] = z01 * z[2];
            G[g][3] = G[g][2] * z[3];
        }

        float hh[4];
#pragma unroll
        for (int w = 0; w < 4; ++w) {
            float fg = sigm(G[0][w]);
            float ig = sigm(G[1][w]);
            float ug = tanh_f(G[2][w]);
            float og = sigm(G[3][w]);
            c[w] = fmaf(fg, c[w], ig * ug);
            hh[w] = og * tanh_f(c[w]);
            h[w] = hh[w];
        }

        float4 hv;
        hv.x = hh[0]; hv.y = hh[1]; hv.z = hh[2]; hv.w = hh[3];
        *(float4*)(outh + (size_t)t * (BB * 4)) = hv;

#pragma unroll
        for (int q = 0; q < 4; ++q) { cur[q] = n1[q]; n1[q] = n2[q]; }
    }

    // final h, c
    float4 hv; hv.x = h[0]; hv.y = h[1]; hv.z = h[2]; hv.w = h[3];
    float4 cv; cv.x = c[0]; cv.y = c[1]; cv.z = c[2]; cv.w = c[3];
    *(float4*)(out + (size_t)TT * BB * 4 + (size_t)b * 4) = hv;
    *(float4*)(out + (size_t)TT * BB * 4 + (size_t)BB * 4 + (size_t)b * 4) = cv;
}

extern "C" void kernel_launch(void* const* d_in, const int* in_sizes, int n_in,
                              void* d_out, int out_size, void* d_ws, size_t ws_size,
                              hipStream_t stream)
{
    const float* x   = (const float*)d_in[0];
    const float* Wf  = (const float*)d_in[1];
    const float* bf  = (const float*)d_in[2];
    const float* thf = (const float*)d_in[3];
    const float* Wi  = (const float*)d_in[4];
    const float* bi  = (const float*)d_in[5];
    const float* thi = (const float*)d_in[6];
    const float* Wu  = (const float*)d_in[7];
    const float* bu  = (const float*)d_in[8];
    const float* thu = (const float*)d_in[9];
    const float* Wo  = (const float*)d_in[10];
    const float* bo  = (const float*)d_in[11];
    const float* tho = (const float*)d_in[12];
    float* Ax = (float*)d_ws;                 // T*B*16 floats = 33.5 MB
    float* outp = (float*)d_out;

    qlstm_phase1<<<dim3((TT * BB) / 256), dim3(256), 0, stream>>>(
        x, Wf, bf, thf, Wi, bi, thi, Wu, bu, thu, Wo, bo, tho, Ax);
    qlstm_phase2<<<dim3(BB / 64), dim3(64), 0, stream>>>(
        Ax, Wf, Wi, Wu, Wo, outp);
}

// Round 2
// 470.397 us; speedup vs baseline: 1.2658x; 1.2658x over previous
//
#include <hip/hip_runtime.h>

#define TT 256
#define BB 2048
#define DIN 128
#define DWROW 132           // D + H
#define INV2PI 0.15915494309189535f
#define LOG2E  1.4426950408889634f

__device__ __forceinline__ const float* rfl_ptr(const float* p) {
    // force pointer into SGPRs so weight loads become s_load (wave-uniform)
    unsigned long long u = (unsigned long long)p;
    unsigned lo = __builtin_amdgcn_readfirstlane((unsigned)u);
    unsigned hi = __builtin_amdgcn_readfirstlane((unsigned)(u >> 32));
    return (const float*)(((unsigned long long)hi << 32) | lo);
}

__device__ __forceinline__ float bperm(int byte_addr, float v) {
    return __int_as_float(__builtin_amdgcn_ds_bpermute(byte_addr, __float_as_int(v)));
}

// ---------------- Phase 1 ----------------
// Ax[row][g*4+w] = (x[row,:] . W_g[w,:128] + b_g[w] + th_g[w]) * INV2PI
// Block = 256 threads (4 waves), tile = 64 rows. Wave wv handles gate wv.
__global__ __launch_bounds__(256) void qlstm_phase1(
    const float* __restrict__ x,
    const float* __restrict__ Wf, const float* __restrict__ bf, const float* __restrict__ thf,
    const float* __restrict__ Wi, const float* __restrict__ bi, const float* __restrict__ thi,
    const float* __restrict__ Wu, const float* __restrict__ bu, const float* __restrict__ thu,
    const float* __restrict__ Wo, const float* __restrict__ bo, const float* __restrict__ tho,
    float* __restrict__ Ax)
{
    __shared__ float xT[DIN][65];            // [j][row], stride 65 kills conflicts

    const int tid = threadIdx.x;
    const size_t tile = blockIdx.x;          // 8192 tiles of 64 rows

    // coalesced stage: 2048 float4 per block, lane-consecutive
    const float4* xg = (const float4*)x + tile * (64 * DIN / 4);
#pragma unroll
    for (int i = 0; i < 8; ++i) {
        int f   = i * 256 + tid;             // 0..2047
        int row = f >> 5;                    // 0..63
        int c4  = f & 31;                    // float4 within row
        float4 v = xg[f];
        xT[4 * c4 + 0][row] = v.x;
        xT[4 * c4 + 1][row] = v.y;
        xT[4 * c4 + 2][row] = v.z;
        xT[4 * c4 + 3][row] = v.w;
    }
    __syncthreads();

    const int wv   = tid >> 6;               // wave id == gate id
    const int lane = tid & 63;               // row within tile

    const float* Wp  = (wv == 0) ? Wf  : (wv == 1) ? Wi  : (wv == 2) ? Wu  : Wo;
    const float* bp  = (wv == 0) ? bf  : (wv == 1) ? bi  : (wv == 2) ? bu  : bo;
    const float* thp = (wv == 0) ? thf : (wv == 1) ? thi : (wv == 2) ? thu : tho;
    const float* Wg  = rfl_ptr(Wp);
    const float* bg  = rfl_ptr(bp);
    const float* thg = rfl_ptr(thp);

    float acc0 = bg[0] + thg[0];
    float acc1 = bg[1] + thg[1];
    float acc2 = bg[2] + thg[2];
    float acc3 = bg[3] + thg[3];

#pragma unroll 8
    for (int j = 0; j < DIN; ++j) {
        float xv = xT[j][lane];
        acc0 = fmaf(xv, Wg[0 * DWROW + j], acc0);
        acc1 = fmaf(xv, Wg[1 * DWROW + j], acc1);
        acc2 = fmaf(xv, Wg[2 * DWROW + j], acc2);
        acc3 = fmaf(xv, Wg[3 * DWROW + j], acc3);
    }

    float4 o;
    o.x = acc0 * INV2PI; o.y = acc1 * INV2PI;
    o.z = acc2 * INV2PI; o.w = acc3 * INV2PI;
    ((float4*)Ax)[(tile * 64 + lane) * 4 + wv] = o;
}

// ---------------- Phase 2 ----------------
// 16 lanes per batch element: lane = g*4 + w. Each lane: 1 cos + 1 act per step.
__global__ __launch_bounds__(64) void qlstm_phase2(
    const float* __restrict__ Ax,
    const float* __restrict__ Wf, const float* __restrict__ Wi,
    const float* __restrict__ Wu, const float* __restrict__ Wo,
    float* __restrict__ out)
{
    const int gtid = blockIdx.x * 64 + threadIdx.x;   // 0..32767
    const int lane = threadIdx.x & 63;
    const int sub  = gtid & 15;
    const int w    = sub & 3;                         // wire / output column
    const int g    = (sub >> 2) & 3;                  // gate
    const int b    = gtid >> 4;                       // batch element

    const float* Wg = (g == 0) ? Wf : (g == 1) ? Wi : (g == 2) ? Wu : Wo;
    // h-part of this lane's angle row, pre-scaled by 1/2pi
    const float wh0 = Wg[w * DWROW + DIN + 0] * INV2PI;
    const float wh1 = Wg[w * DWROW + DIN + 1] * INV2PI;
    const float wh2 = Wg[w * DWROW + DIN + 2] * INV2PI;
    const float wh3 = Wg[w * DWROW + DIN + 3] * INV2PI;

    // activation constants: u-gate -> tanh, else sigmoid
    // act(x) = A + B * rcp(1 + exp2(K*x))
    const bool  isU = (g == 2);
    const float Ac  = isU ? 1.0f : 0.0f;
    const float Bc  = isU ? -2.0f : 1.0f;
    const float Kc  = isU ? (2.0f * LOG2E) : (-LOG2E);

    // bpermute byte addresses (precomputed, reused every step)
    const int gb  = (lane & ~3) << 2;    // gate-quad base
    const int az0 = gb, az1 = gb + 4, az2 = gb + 8, az3 = gb + 12;
    const int bb16 = (lane & ~15) << 2;  // batch-group base
    const int af = bb16 + (w << 2);
    const int ai = af + 16;
    const int au = af + 32;
    const int ao = af + 48;

    const size_t S = (size_t)BB * 16;    // Ax floats per timestep
    const float* ap = Ax + (size_t)b * 16 + sub;

    // prefetch depth 4
    float a0 = ap[0 * S], a1 = ap[1 * S], a2 = ap[2 * S], a3 = ap[3 * S];

    float hv0 = 0.f, hv1 = 0.f, hv2 = 0.f, hv3 = 0.f;  // h[0..3] (all lanes)
    float cst = 0.f;                                    // c[w]
    float h   = 0.f;                                    // h[w]

    for (int t = 0; t < TT; ++t) {
        float ax = a0;
        a0 = a1; a1 = a2; a2 = a3;
        int tn = t + 4; if (tn > TT - 1) tn = TT - 1;
        a3 = ap[(size_t)tn * S];

        // angle (already in revolutions)
        float ang = ax;
        ang = fmaf(hv0, wh0, ang);
        ang = fmaf(hv1, wh1, ang);
        ang = fmaf(hv2, wh2, ang);
        ang = fmaf(hv3, wh3, ang);
        float z = __builtin_amdgcn_cosf(ang);

        // gather all 4 z within gate-quad
        float z0 = bperm(az0, z);
        float z1 = bperm(az1, z);
        float z2 = bperm(az2, z);
        float z3 = bperm(az3, z);

        // output-column product for this lane's w
        float c0    = z1 * z2 * z3;
        float p01   = z0 * z1;
        float p012  = p01 * z2;
        float p0123 = p012 * z3;
        float G = (w == 0) ? c0 : (w == 1) ? p01 : (w == 2) ? p012 : p0123;

        // activation
        float e   = __builtin_amdgcn_exp2f(Kc * G);
        float act = fmaf(Bc, __builtin_amdgcn_rcpf(1.0f + e), Ac);

        // gather f,i,u,o for this w
        float fg = bperm(af, act);
        float ig = bperm(ai, act);
        float ug = bperm(au, act);
        float og = bperm(ao, act);

        cst = fmaf(fg, cst, ig * ug);
        float ec = __builtin_amdgcn_exp2f((2.0f * LOG2E) * cst);
        float th = 1.0f - 2.0f * __builtin_amdgcn_rcpf(1.0f + ec);
        h = og * th;

        if (g == 0)
            out[(size_t)t * (BB * 4) + b * 4 + w] = h;

        // broadcast h[0..3] for next step's angle FMA
        hv0 = bperm(az0, h);
        hv1 = bperm(az1, h);
        hv2 = bperm(az2, h);
        hv3 = bperm(az3, h);
    }

    if (g == 0) {
        out[(size_t)TT * BB * 4 + b * 4 + w]          = h;
        out[(size_t)TT * BB * 4 + BB * 4 + b * 4 + w] = cst;
    }
}

extern "C" void kernel_launch(void* const* d_in, const int* in_sizes, int n_in,
                              void* d_out, int out_size, void* d_ws, size_t ws_size,
                              hipStream_t stream)
{
    const float* x   = (const float*)d_in[0];
    const float* Wf  = (const float*)d_in[1];
    const float* bf  = (const float*)d_in[2];
    const float* thf = (const float*)d_in[3];
    const float* Wi  = (const float*)d_in[4];
    const float* bi  = (const float*)d_in[5];
    const float* thi = (const float*)d_in[6];
    const float* Wu  = (const float*)d_in[7];
    const float* bu  = (const float*)d_in[8];
    const float* thu = (const float*)d_in[9];
    const float* Wo  = (const float*)d_in[10];
    const float* bo  = (const float*)d_in[11];
    const float* tho = (const float*)d_in[12];
    float* Ax   = (float*)d_ws;               // T*B*16 floats = 33.5 MB
    float* outp = (float*)d_out;

    qlstm_phase1<<<dim3((TT * BB) / 64), dim3(256), 0, stream>>>(
        x, Wf, bf, thf, Wi, bi, thi, Wu, bu, thu, Wo, bo, tho, Ax);
    qlstm_phase2<<<dim3((BB * 16) / 64), dim3(64), 0, stream>>>(
        Ax, Wf, Wi, Wu, Wo, outp);
}

// Round 3
// 469.790 us; speedup vs baseline: 1.2675x; 1.0013x over previous
//
#include <hip/hip_runtime.h>

#define TT 256
#define BB 2048
#define DIN 128
#define DWROW 132           // D + H
#define INV2PI 0.15915494309189535f
#define LOG2E  1.4426950408889634f

__device__ __forceinline__ const float* rfl_ptr(const float* p) {
    unsigned long long u = (unsigned long long)p;
    unsigned lo = __builtin_amdgcn_readfirstlane((unsigned)u);
    unsigned hi = __builtin_amdgcn_readfirstlane((unsigned)(u >> 32));
    return (const float*)(((unsigned long long)hi << 32) | lo);
}

// quad broadcast via DPP: every lane of each 4-lane quad gets lane j's value.
// quad_perm[j,j,j,j] ctrl = j*0x55 -- symmetric, no shift-direction ambiguity.
#define DPP_BCAST(dst, src, j) \
    dst = __int_as_float(__builtin_amdgcn_update_dpp( \
        0, __float_as_int(src), (j) * 0x55, 0xF, 0xF, true))

__device__ __forceinline__ float sigm(float x) {
    float e = __builtin_amdgcn_exp2f(-LOG2E * x);
    return __builtin_amdgcn_rcpf(1.0f + e);
}
__device__ __forceinline__ float tanh_f(float x) {
    float e = __builtin_amdgcn_exp2f((2.0f * LOG2E) * x);
    return 1.0f - 2.0f * __builtin_amdgcn_rcpf(1.0f + e);
}

// ---------------- Phase 1 (unchanged: near memory roofline) ----------------
// Ax[row][g*4+w] = (x[row,:] . W_g[w,:128] + b_g[w] + th_g[w]) * INV2PI
__global__ __launch_bounds__(256) void qlstm_phase1(
    const float* __restrict__ x,
    const float* __restrict__ Wf, const float* __restrict__ bf, const float* __restrict__ thf,
    const float* __restrict__ Wi, const float* __restrict__ bi, const float* __restrict__ thi,
    const float* __restrict__ Wu, const float* __restrict__ bu, const float* __restrict__ thu,
    const float* __restrict__ Wo, const float* __restrict__ bo, const float* __restrict__ tho,
    float* __restrict__ Ax)
{
    __shared__ float xT[DIN][65];

    const int tid = threadIdx.x;
    const size_t tile = blockIdx.x;

    const float4* xg = (const float4*)x + tile * (64 * DIN / 4);
#pragma unroll
    for (int i = 0; i < 8; ++i) {
        int f   = i * 256 + tid;
        int row = f >> 5;
        int c4  = f & 31;
        float4 v = xg[f];
        xT[4 * c4 + 0][row] = v.x;
        xT[4 * c4 + 1][row] = v.y;
        xT[4 * c4 + 2][row] = v.z;
        xT[4 * c4 + 3][row] = v.w;
    }
    __syncthreads();

    const int wv   = tid >> 6;
    const int lane = tid & 63;

    const float* Wp  = (wv == 0) ? Wf  : (wv == 1) ? Wi  : (wv == 2) ? Wu  : Wo;
    const float* bp  = (wv == 0) ? bf  : (wv == 1) ? bi  : (wv == 2) ? bu  : bo;
    const float* thp = (wv == 0) ? thf : (wv == 1) ? thi : (wv == 2) ? thu : tho;
    const float* Wg  = rfl_ptr(Wp);
    const float* bg  = rfl_ptr(bp);
    const float* thg = rfl_ptr(thp);

    float acc0 = bg[0] + thg[0];
    float acc1 = bg[1] + thg[1];
    float acc2 = bg[2] + thg[2];
    float acc3 = bg[3] + thg[3];

#pragma unroll 8
    for (int j = 0; j < DIN; ++j) {
        float xv = xT[j][lane];
        acc0 = fmaf(xv, Wg[0 * DWROW + j], acc0);
        acc1 = fmaf(xv, Wg[1 * DWROW + j], acc1);
        acc2 = fmaf(xv, Wg[2 * DWROW + j], acc2);
        acc3 = fmaf(xv, Wg[3 * DWROW + j], acc3);
    }

    float4 o;
    o.x = acc0 * INV2PI; o.y = acc1 * INV2PI;
    o.z = acc2 * INV2PI; o.w = acc3 * INV2PI;
    ((float4*)Ax)[(tile * 64 + lane) * 4 + wv] = o;
}

// ---------------- Phase 2: 4 lanes per batch element, all-DPP cross-lane ---
// lane = wire w; each lane computes all 4 gates for its wire.
__global__ __launch_bounds__(64) void qlstm_phase2(
    const float* __restrict__ Ax,
    const float* __restrict__ Wf, const float* __restrict__ Wi,
    const float* __restrict__ Wu, const float* __restrict__ Wo,
    float* __restrict__ out)
{
    const int gtid = blockIdx.x * 64 + threadIdx.x;   // 0..8191
    const int w = gtid & 3;                           // wire
    const int b = gtid >> 2;                          // batch element

    const float* Ws[4] = {Wf, Wi, Wu, Wo};
    // h-part of each gate's row for this wire, pre-scaled by 1/2pi
    float wh[4][4];
#pragma unroll
    for (int g = 0; g < 4; ++g)
#pragma unroll
        for (int j = 0; j < 4; ++j)
            wh[g][j] = Ws[g][w * DWROW + DIN + j] * INV2PI;

    const size_t S = (size_t)BB * 16;                 // Ax floats per timestep
    const float* ap = Ax + (size_t)b * 16 + w;

    // prefetch ring, depth 4: ar[d][g]
    float ar[4][4];
#pragma unroll
    for (int d = 0; d < 4; ++d)
#pragma unroll
        for (int g = 0; g < 4; ++g)
            ar[d][g] = ap[(size_t)d * S + g * 4];

    float hv0 = 0.f, hv1 = 0.f, hv2 = 0.f, hv3 = 0.f; // h[0..3] (shared)
    float cst = 0.f;                                  // c[w]
    float h   = 0.f;                                  // h[w]

    for (int t4 = 0; t4 < TT / 4; ++t4) {
#pragma unroll
        for (int k = 0; k < 4; ++k) {
            const int t = 4 * t4 + k;
            float a0 = ar[k][0], a1 = ar[k][1], a2 = ar[k][2], a3 = ar[k][3];
            int tn = t + 4; if (tn > TT - 1) tn = TT - 1;
#pragma unroll
            for (int g = 0; g < 4; ++g)
                ar[k][g] = ap[(size_t)tn * S + g * 4];

            // angles (revolutions) and cosines, all 4 gates
            float z[4];
#pragma unroll
            for (int g = 0; g < 4; ++g) {
                float ang = (g == 0) ? a0 : (g == 1) ? a1 : (g == 2) ? a2 : a3;
                ang = fmaf(hv0, wh[g][0], ang);
                ang = fmaf(hv1, wh[g][1], ang);
                ang = fmaf(hv2, wh[g][2], ang);
                ang = fmaf(hv3, wh[g][3], ang);
                z[g] = __builtin_amdgcn_cosf(ang);
            }

            // per gate: share z across the quad (DPP broadcasts), build G[w]
            float G[4];
#pragma unroll
            for (int g = 0; g < 4; ++g) {
                float q0, q1, q2, q3;
                DPP_BCAST(q0, z[g], 0);
                DPP_BCAST(q1, z[g], 1);
                DPP_BCAST(q2, z[g], 2);
                DPP_BCAST(q3, z[g], 3);
                float p01   = q0 * q1;
                float p012  = p01 * q2;
                float p0123 = p012 * q3;
                float c0    = q1 * q2 * q3;
                G[g] = (w == 0) ? c0 : (w == 1) ? p01 : (w == 2) ? p012 : p0123;
            }

            float fg = sigm(G[0]);
            float ig = sigm(G[1]);
            float ug = tanh_f(G[2]);
            float og = sigm(G[3]);

            cst = fmaf(fg, cst, ig * ug);
            float th = tanh_f(cst);
            h = og * th;

            out[(size_t)t * (BB * 4) + b * 4 + w] = h;   // 64 consecutive floats/wave

            // share h across the quad for next step's angles
            DPP_BCAST(hv0, h, 0);
            DPP_BCAST(hv1, h, 1);
            DPP_BCAST(hv2, h, 2);
            DPP_BCAST(hv3, h, 3);
        }
    }

    out[(size_t)TT * BB * 4 + b * 4 + w]          = h;
    out[(size_t)TT * BB * 4 + BB * 4 + b * 4 + w] = cst;
}

extern "C" void kernel_launch(void* const* d_in, const int* in_sizes, int n_in,
                              void* d_out, int out_size, void* d_ws, size_t ws_size,
                              hipStream_t stream)
{
    const float* x   = (const float*)d_in[0];
    const float* Wf  = (const float*)d_in[1];
    const float* bf  = (const float*)d_in[2];
    const float* thf = (const float*)d_in[3];
    const float* Wi  = (const float*)d_in[4];
    const float* bi  = (const float*)d_in[5];
    const float* thi = (const float*)d_in[6];
    const float* Wu  = (const float*)d_in[7];
    const float* bu  = (const float*)d_in[8];
    const float* thu = (const float*)d_in[9];
    const float* Wo  = (const float*)d_in[10];
    const float* bo  = (const float*)d_in[11];
    const float* tho = (const float*)d_in[12];
    float* Ax   = (float*)d_ws;               // T*B*16 floats = 33.5 MB
    float* outp = (float*)d_out;

    qlstm_phase1<<<dim3((TT * BB) / 64), dim3(256), 0, stream>>>(
        x, Wf, bf, thf, Wi, bi, thi, Wu, bu, thu, Wo, bo, tho, Ax);
    qlstm_phase2<<<dim3((BB * 4) / 64), dim3(64), 0, stream>>>(
        Ax, Wf, Wi, Wu, Wo, outp);
}